// Round 1
// baseline (568.760 us; speedup 1.0000x reference)
//
#include <hip/hip_runtime.h>

#define IN_DIM   2048
#define OUT_DIM  4096
#define MEM_LEN  32768
#define BETA     5000.0f

// workspace layout (float offsets)
#define WS_SUM    0        // [2048]  column sums of mem_data
#define WS_SUMSQ  2048     // [2048]  column sums of squares
#define WS_ACC    4096     // [4096]  GEMV accumulator (init = b_enc)
#define WS_ENC    8192     // [4096]  tanh(enc)
#define WS_NEW    12288    // [2048]  normalized query
#define WS_MIN    14336    // [1]     min distance (float bits as uint)

// ---------------------------------------------------------------- init
__global__ void k_init(float* __restrict__ ws, const float* __restrict__ b_enc) {
    int t = blockIdx.x * 256 + threadIdx.x;
    if (t < IN_DIM) { ws[WS_SUM + t] = 0.0f; ws[WS_SUMSQ + t] = 0.0f; }
    if (t < OUT_DIM) ws[WS_ACC + t] = b_enc[t];
    if (t == 0) ((unsigned int*)ws)[WS_MIN] = 0x7F800000u;  // +inf
}

// ------------------------- fused: column stats of mem_data + copy to out
// grid (2, 512), block 256. Each thread owns one float4-column (512 total)
// for a 64-row chunk. float4 loads (input aligned), scalar stores (output
// region is d_out+offset with odd float offset -> not 16B aligned).
__global__ void k_stats_copy(const float* __restrict__ md,
                             float* __restrict__ out_md,
                             float* __restrict__ ws) {
    const int f4c = blockIdx.x * 256 + threadIdx.x;   // 0..511
    const int r0 = blockIdx.y * 64;
    const float4* md4 = (const float4*)md;
    float s0 = 0, s1 = 0, s2 = 0, s3 = 0;
    float q0 = 0, q1 = 0, q2 = 0, q3 = 0;
#pragma unroll 4
    for (int i = 0; i < 64; ++i) {
        size_t r = (size_t)(r0 + i);
        float4 v = md4[r * 512 + f4c];
        s0 += v.x; q0 += v.x * v.x;
        s1 += v.y; q1 += v.y * v.y;
        s2 += v.z; q2 += v.z * v.z;
        s3 += v.w; q3 += v.w * v.w;
        size_t ob = r * 2048 + (size_t)f4c * 4;
        out_md[ob + 0] = v.x; out_md[ob + 1] = v.y;
        out_md[ob + 2] = v.z; out_md[ob + 3] = v.w;
    }
    int c = f4c * 4;
    atomicAdd(&ws[WS_SUM + c + 0], s0);  atomicAdd(&ws[WS_SUMSQ + c + 0], q0);
    atomicAdd(&ws[WS_SUM + c + 1], s1);  atomicAdd(&ws[WS_SUMSQ + c + 1], q1);
    atomicAdd(&ws[WS_SUM + c + 2], s2);  atomicAdd(&ws[WS_SUMSQ + c + 2], q2);
    atomicAdd(&ws[WS_SUM + c + 3], s3);  atomicAdd(&ws[WS_SUMSQ + c + 3], q3);
}

// ---------------------------------------------------------------- new = (x-mean)/std
__global__ void k_new(const float* __restrict__ x, float* __restrict__ ws) {
    int i = blockIdx.x * 256 + threadIdx.x;
    if (i >= IN_DIM) return;
    float s = ws[WS_SUM + i], q = ws[WS_SUMSQ + i];
    float mean = s / (float)MEM_LEN;
    float var = (q - s * mean) / (float)(MEM_LEN - 1);   // ddof=1
    float sd = sqrtf(fmaxf(var, 0.0f));
    ws[WS_NEW + i] = (sd == 0.0f) ? 0.0f : (x[i] - mean) / sd;
}

// ---------------------------------------------------------------- GEMV partials
// grid (4, 64), block 256: thread owns 4 output cols (float4 of W row),
// 32-row i-chunk per blockIdx.y, atomicAdd partials into WS_ACC.
__global__ void k_gemv(const float* __restrict__ W, float* __restrict__ ws) {
    const int j4 = blockIdx.x * 256 + threadIdx.x;    // 0..1023
    const int i0 = blockIdx.y * 32;
    const float4* W4 = (const float4*)W;
    float a0 = 0, a1 = 0, a2 = 0, a3 = 0;
#pragma unroll 8
    for (int k = 0; k < 32; ++k) {
        int i = i0 + k;
        float nv = ws[WS_NEW + i];
        float4 w = W4[(size_t)i * 1024 + j4];
        a0 += nv * w.x; a1 += nv * w.y; a2 += nv * w.z; a3 += nv * w.w;
    }
    int j = j4 * 4;
    atomicAdd(&ws[WS_ACC + j + 0], a0);
    atomicAdd(&ws[WS_ACC + j + 1], a1);
    atomicAdd(&ws[WS_ACC + j + 2], a2);
    atomicAdd(&ws[WS_ACC + j + 3], a3);
}

// ---------------------------------------------------------------- tanh
__global__ void k_tanh(float* __restrict__ ws) {
    int j = blockIdx.x * 256 + threadIdx.x;
    if (j < OUT_DIM) ws[WS_ENC + j] = tanhf(ws[WS_ACC + j]);
}

// ------------------- fused: per-row L1 distance + copy memory to out
// One wave per row; block 256 = 4 rows; grid 8192.
__global__ void k_dist_copy(const float* __restrict__ mem,
                            float* __restrict__ out_mem,
                            float* __restrict__ ws) {
    const int lane = threadIdx.x & 63;
    const int wid = threadIdx.x >> 6;
    const size_t r = (size_t)blockIdx.x * 4 + wid;
    const float4* m4 = (const float4*)mem;
    const float4* e4 = (const float4*)(ws + WS_ENC);
    float* orow = out_mem + r * OUT_DIM;
    float acc = 0.0f;
#pragma unroll 4
    for (int k = 0; k < 16; ++k) {
        int c4 = lane + k * 64;          // 0..1023
        float4 m = m4[r * 1024 + c4];
        float4 e = e4[c4];
        acc += fabsf(m.x - e.x) + fabsf(m.y - e.y) +
               fabsf(m.z - e.z) + fabsf(m.w - e.w);
        int ob = c4 * 4;
        orow[ob + 0] = m.x; orow[ob + 1] = m.y;
        orow[ob + 2] = m.z; orow[ob + 3] = m.w;
    }
    // wave sum -> row distance
    for (int off = 32; off >= 1; off >>= 1)
        acc += __shfl_down(acc, off, 64);
    if (lane == 0)
        atomicMin((unsigned int*)ws + WS_MIN, __float_as_uint(acc));  // acc >= 0
}

// ---------------------------------------------------------------- finalize
__global__ void k_final(const float* __restrict__ x, const int* __restrict__ count,
                        const float* __restrict__ ws, float* __restrict__ d_out) {
    float loss = __uint_as_float(((const unsigned int*)ws)[WS_MIN]);
    if (threadIdx.x == 0) d_out[0] = loss;
    if (loss <= BETA) {
        int pos = count[0] % MEM_LEN;
        float* outM = d_out + 1;
        float* outMD = d_out + 1 + (size_t)MEM_LEN * OUT_DIM;
        for (int j = threadIdx.x; j < OUT_DIM; j += 256)
            outM[(size_t)pos * OUT_DIM + j] = ws[WS_ENC + j];
        for (int i = threadIdx.x; i < IN_DIM; i += 256)
            outMD[(size_t)pos * IN_DIM + i] = x[i];
    }
}

extern "C" void kernel_launch(void* const* d_in, const int* in_sizes, int n_in,
                              void* d_out, int out_size, void* d_ws, size_t ws_size,
                              hipStream_t stream) {
    const float* x        = (const float*)d_in[0];
    const float* memory   = (const float*)d_in[1];
    const float* mem_data = (const float*)d_in[2];
    const float* W_enc    = (const float*)d_in[3];
    const float* b_enc    = (const float*)d_in[4];
    const int*   count    = (const int*)d_in[5];
    float* out = (float*)d_out;
    float* ws  = (float*)d_ws;

    float* out_mem = out + 1;                                   // [32768][4096]
    float* out_md  = out + 1 + (size_t)MEM_LEN * OUT_DIM;       // [32768][2048]

    k_init<<<16, 256, 0, stream>>>(ws, b_enc);
    k_stats_copy<<<dim3(2, 512), 256, 0, stream>>>(mem_data, out_md, ws);
    k_new<<<8, 256, 0, stream>>>(x, ws);
    k_gemv<<<dim3(4, 64), 256, 0, stream>>>(W_enc, ws);
    k_tanh<<<16, 256, 0, stream>>>(ws);
    k_dist_copy<<<8192, 256, 0, stream>>>(memory, out_mem, ws);
    k_final<<<1, 256, 0, stream>>>(x, count, ws, out);
}

// Round 2
// 391.607 us; speedup vs baseline: 1.4524x; 1.4524x over previous
//
#include <hip/hip_runtime.h>

#define IN_DIM   2048
#define OUT_DIM  4096
#define MEM_LEN  32768
#define BETA     5000.0f

// workspace layout (float offsets), ~3.03 MB total
#define WS_PS    0                        // [128][2048] stats partial sums
#define WS_PQ    (WS_PS + 128*2048)       // [128][2048] stats partial sum-squares
#define WS_PG    (WS_PQ + 128*2048)       // [64][4096]  gemv partials
#define WS_NEW   (WS_PG + 64*4096)        // [2048] normalized query
#define WS_ENC   (WS_NEW + 2048)          // [4096] tanh(enc)
#define WS_MINB  (WS_ENC + 4096)          // [64] bucket minima (float bits as uint)

// ---------------------------------------------------------------- init
__global__ void k_init(float* __restrict__ ws) {
    if (threadIdx.x < 64)
        ((unsigned int*)ws)[WS_MINB + threadIdx.x] = 0x7F800000u;  // +inf
}

// ---------------- fused: column partial stats of mem_data + copy to out
// grid (8,128), block 256. Thread owns one dword column (c = bx*256+tid),
// 256-row chunk per blockIdx.y. Loads AND stores are lane-consecutive
// coalesced dwords (output base is only 4B-aligned, so dword is the widest
// legal store). Partials written to ws, no atomics.
__global__ void k_stats_copy(const float* __restrict__ md,
                             float* __restrict__ out_md,
                             float* __restrict__ ws) {
    const int c  = blockIdx.x * 256 + threadIdx.x;   // 0..2047
    const int r0 = blockIdx.y * 256;
    const float* p = md + (size_t)r0 * IN_DIM + c;
    float* o = out_md + (size_t)r0 * IN_DIM + c;
    float s = 0.0f, q = 0.0f;
#pragma unroll 4
    for (int i = 0; i < 256; ++i) {
        float v = __builtin_nontemporal_load(p + (size_t)i * IN_DIM);
        s += v; q += v * v;
        __builtin_nontemporal_store(v, o + (size_t)i * IN_DIM);
    }
    ws[WS_PS + blockIdx.y * IN_DIM + c] = s;
    ws[WS_PQ + blockIdx.y * IN_DIM + c] = q;
}

// ---------------------------------------------------------------- new = (x-mean)/std
__global__ void k_new(const float* __restrict__ x, float* __restrict__ ws) {
    int c = blockIdx.x * 256 + threadIdx.x;
    float s = 0.0f, q = 0.0f;
    for (int y = 0; y < 128; ++y) {
        s += ws[WS_PS + y * IN_DIM + c];
        q += ws[WS_PQ + y * IN_DIM + c];
    }
    float mean = s * (1.0f / (float)MEM_LEN);
    float var  = (q - s * mean) * (1.0f / (float)(MEM_LEN - 1));  // ddof=1
    float sd   = sqrtf(fmaxf(var, 0.0f));
    ws[WS_NEW + c] = (sd == 0.0f) ? 0.0f : (x[c] - mean) / sd;
}

// ---------------------------------------------------------------- GEMV partials
// grid (4,64), block 256: thread owns float4 of W row (aligned input),
// 32-row chunk per blockIdx.y; float4 partial store to ws (aligned).
__global__ void k_gemv(const float* __restrict__ W, float* __restrict__ ws) {
    const int j4 = blockIdx.x * 256 + threadIdx.x;    // 0..1023
    const int i0 = blockIdx.y * 32;
    const float4* W4 = (const float4*)W;
    float4 a = make_float4(0.f, 0.f, 0.f, 0.f);
#pragma unroll 8
    for (int k = 0; k < 32; ++k) {
        float nv = ws[WS_NEW + i0 + k];
        float4 w = W4[(size_t)(i0 + k) * 1024 + j4];
        a.x += nv * w.x; a.y += nv * w.y; a.z += nv * w.z; a.w += nv * w.w;
    }
    ((float4*)(ws + WS_PG))[(size_t)blockIdx.y * 1024 + j4] = a;
}

// ------------------------------------------------ reduce gemv + bias + tanh
__global__ void k_enc(const float* __restrict__ b_enc, float* __restrict__ ws) {
    int j = blockIdx.x * 256 + threadIdx.x;
    float s = b_enc[j];
    for (int y = 0; y < 64; ++y) s += ws[WS_PG + y * OUT_DIM + j];
    ws[WS_ENC + j] = tanhf(s);
}

// ------------------- fused: per-row L1 distance + copy memory to out
// Wave per row (block 256 = 4 rows, grid 8192). Lane owns dword columns
// c = k*64+lane: loads and stores both lane-consecutive coalesced dwords.
// Wave shuffle-reduce -> block LDS reduce -> 64-bucket atomicMin.
__global__ void k_dist_copy(const float* __restrict__ mem,
                            float* __restrict__ out_mem,
                            float* __restrict__ ws) {
    const int lane = threadIdx.x & 63;
    const int wid  = threadIdx.x >> 6;
    const size_t r = (size_t)blockIdx.x * 4 + wid;
    const float* p = mem + r * OUT_DIM;
    float* o = out_mem + r * OUT_DIM;
    float acc = 0.0f;
#pragma unroll 8
    for (int k = 0; k < 64; ++k) {
        int c = k * 64 + lane;
        float m = __builtin_nontemporal_load(p + c);
        acc += fabsf(m - ws[WS_ENC + c]);
        __builtin_nontemporal_store(m, o + c);
    }
    for (int off = 32; off >= 1; off >>= 1)
        acc += __shfl_down(acc, off, 64);
    __shared__ float wmin[4];
    if (lane == 0) wmin[wid] = acc;
    __syncthreads();
    if (threadIdx.x == 0) {
        float b = fminf(fminf(wmin[0], wmin[1]), fminf(wmin[2], wmin[3]));
        atomicMin((unsigned int*)ws + WS_MINB + (blockIdx.x & 63),
                  __float_as_uint(b));   // b >= 0 so uint-order == float-order
    }
}

// ---------------------------------------------------------------- finalize
__global__ void k_final(const float* __restrict__ x, const int* __restrict__ count,
                        const float* __restrict__ ws, float* __restrict__ d_out) {
    __shared__ float sl;
    int t = threadIdx.x;
    if (t < 64) {
        float v = __uint_as_float(((const unsigned int*)ws)[WS_MINB + t]);
        for (int off = 32; off >= 1; off >>= 1)
            v = fminf(v, __shfl_down(v, off, 64));
        if (t == 0) { d_out[0] = v; sl = v; }
    }
    __syncthreads();
    float loss = sl;
    if (loss <= BETA) {
        int pos = count[0] % MEM_LEN;
        float* outM  = d_out + 1;
        float* outMD = d_out + 1 + (size_t)MEM_LEN * OUT_DIM;
        for (int j = t; j < OUT_DIM; j += 256)
            outM[(size_t)pos * OUT_DIM + j] = ws[WS_ENC + j];
        for (int i = t; i < IN_DIM; i += 256)
            outMD[(size_t)pos * IN_DIM + i] = x[i];
    }
}

extern "C" void kernel_launch(void* const* d_in, const int* in_sizes, int n_in,
                              void* d_out, int out_size, void* d_ws, size_t ws_size,
                              hipStream_t stream) {
    const float* x        = (const float*)d_in[0];
    const float* memory   = (const float*)d_in[1];
    const float* mem_data = (const float*)d_in[2];
    const float* W_enc    = (const float*)d_in[3];
    const float* b_enc    = (const float*)d_in[4];
    const int*   count    = (const int*)d_in[5];
    float* out = (float*)d_out;
    float* ws  = (float*)d_ws;

    float* out_mem = out + 1;                                   // [32768][4096]
    float* out_md  = out + 1 + (size_t)MEM_LEN * OUT_DIM;       // [32768][2048]

    k_init<<<1, 64, 0, stream>>>(ws);
    k_stats_copy<<<dim3(8, 128), 256, 0, stream>>>(mem_data, out_md, ws);
    k_new<<<8, 256, 0, stream>>>(x, ws);
    k_gemv<<<dim3(4, 64), 256, 0, stream>>>(W_enc, ws);
    k_enc<<<16, 256, 0, stream>>>(b_enc, ws);
    k_dist_copy<<<8192, 256, 0, stream>>>(memory, out_mem, ws);
    k_final<<<1, 256, 0, stream>>>(x, count, ws, out);
}